// Round 8
// baseline (1037.591 us; speedup 1.0000x reference)
//
#include <hip/hip_runtime.h>
#include <hip/hip_cooperative_groups.h>
#include <hip/hip_bf16.h>
#include <math.h>

#define C_N   2000
#define DIMN  128
#define DM    256
#define B_N   8
#define HT    16
#define S_N   64
#define NSEQ  136
#define DFF   1024
#define NEDGE (B_N*HT*(S_N-1))   // 8064

typedef __hip_bfloat16 bf16;
typedef short bf16x8 __attribute__((ext_vector_type(8)));
typedef float f32x4  __attribute__((ext_vector_type(4)));

namespace cg = cooperative_groups;

#define GLOAD_LDS16(gp, lp) \
    __builtin_amdgcn_global_load_lds((const __attribute__((address_space(1))) void*)(gp), \
                                     (__attribute__((address_space(3))) void*)(lp), 16, 0, 0)

__device__ __forceinline__ short f2bf(float v) {
    bf16 t = (bf16)v;
    return *reinterpret_cast<short*>(&t);
}

// =================== shared args ===================
struct MegaArgs {
    const int *hist, *cur;
    const float *emb, *nullE, *gcn_b, *ab, *fb1, *fb2, *lns, *lnb, *wca_b, *ial_b;
    const float *w_aw, *w_fw1, *w_fw2, *w_wca, *w_gcn, *w_ial;
    float *dvec, *maskb, *temp, *Y, *Eg, *Xenc, *SE, *out;
    bf16 *embbf, *wbf_aw, *wbf_fw1, *wbf_fw2, *wbf_wca, *wbf_gcn, *wbf_ial;
    bf16 *Xbf, *Abf, *Hbf, *QKV, *finalb;
};

// =================== device bodies (single source of truth) ===================

// ---- weight transpose tile: (K,N) f32 -> (N,K) bf16, one 32x32 tile ----
__device__ __forceinline__ void transp_unit(const float* __restrict__ src, bf16* __restrict__ dst,
                                            int K, int N, int tileid, float (*tl)[33]) {
    int tx = threadIdx.x & 31, ty = (threadIdx.x >> 5) & 7;
    int tn = N >> 5;
    int per = (K >> 5) * tn;
    int mat = tileid / per, t2 = tileid % per;
    int tyy = t2 / tn, txx = t2 % tn;
    const float* s = src + (size_t)mat * K * N;
    bf16* d = dst + (size_t)mat * N * K;
    int k0 = tyy * 32, n0 = txx * 32;
    #pragma unroll
    for (int j = 0; j < 32; j += 8)
        tl[ty + j][tx] = s[(size_t)(k0 + ty + j) * N + n0 + tx];
    __syncthreads();
    #pragma unroll
    for (int j = 0; j < 32; j += 8)
        d[(size_t)(n0 + ty + j) * K + k0 + tx] = (bf16)tl[tx][ty + j];
    __syncthreads();   // tl reused by next unit in persistent loop
}

// ---- 128x128 MFMA GEMM tile (dbuf + prefetch). EPI: 1=bias 2=relu 4=resid(f32,ldc)
//      8=bf16 out 16=col-mask(col<nreal). smem needs 65536 B. ----
template<int EPI>
__device__ __forceinline__ void bgemm2_tile(
        const bf16* __restrict__ A, const bf16* __restrict__ Bt,
        const float* __restrict__ bias, const float* __restrict__ resid,
        void* __restrict__ Cout, int m0, int n0, int K, int ldc, int nreal, char* smemc)
{
    bf16* As = (bf16*)smemc;            // [2][8192]
    bf16* Bs = (bf16*)(smemc + 32768);  // [2][8192]
    int tid = threadIdx.x;
    int wid = tid >> 6, lane = tid & 63;
    int wr = wid >> 1, wc = wid & 1;
    int lr = lane >> 3, lc = lane & 7;
    int gc = lc ^ lr;
    f32x4 acc[4][4] = {};
    int nkt = K >> 6;

#define STAGE2(kt, buf) { \
    int kb = (kt) << 6; \
    _Pragma("unroll") \
    for (int s = 0; s < 4; ++s) { \
        int seg = wid * 4 + s; int row = seg * 8 + lr; \
        GLOAD_LDS16(A + (size_t)(m0 + row) * K + kb + gc * 8, As + (buf) * 8192 + seg * 512); \
    } \
    _Pragma("unroll") \
    for (int s = 0; s < 4; ++s) { \
        int seg = wid * 4 + s; int row = seg * 8 + lr; \
        GLOAD_LDS16(Bt + (size_t)(n0 + row) * K + kb + gc * 8, Bs + (buf) * 8192 + seg * 512); \
    } }

    STAGE2(0, 0);
    __syncthreads();
    int cur = 0;
    for (int kt = 0; kt < nkt; ++kt) {
        if (kt + 1 < nkt) STAGE2(kt + 1, cur ^ 1);
        #pragma unroll
        for (int kk = 0; kk < 2; ++kk) {
            bf16x8 af[4], bfr[4];
            int c = kk * 4 + (lane >> 4);
            #pragma unroll
            for (int m = 0; m < 4; ++m) {
                int row = wr * 64 + m * 16 + (lane & 15);
                af[m] = *(const bf16x8*)(As + cur * 8192 + row * 64 + (c ^ (row & 7)) * 8);
            }
            #pragma unroll
            for (int n = 0; n < 4; ++n) {
                int row = wc * 64 + n * 16 + (lane & 15);
                bfr[n] = *(const bf16x8*)(Bs + cur * 8192 + row * 64 + (c ^ (row & 7)) * 8);
            }
            #pragma unroll
            for (int m = 0; m < 4; ++m)
                #pragma unroll
                for (int n = 0; n < 4; ++n)
                    acc[m][n] = __builtin_amdgcn_mfma_f32_16x16x32_bf16(af[m], bfr[n], acc[m][n], 0, 0, 0);
        }
        __syncthreads();
        cur ^= 1;
    }
#undef STAGE2
    int cl = lane & 15, ch = lane >> 4;
    #pragma unroll
    for (int n = 0; n < 4; ++n) {
        int col = n0 + wc * 64 + n * 16 + cl;
        if ((EPI & 16) && col >= nreal) continue;
        float bv = (EPI & 1) ? bias[col] : 0.f;
        #pragma unroll
        for (int m = 0; m < 4; ++m) {
            #pragma unroll
            for (int j = 0; j < 4; ++j) {
                int row = m0 + wr * 64 + m * 16 + ch * 4 + j;
                float v = acc[m][n][j] + bv;
                if (EPI & 4) v += resid[(size_t)row * ldc + col];
                if (EPI & 2) v = fmaxf(v, 0.f);
                if (EPI & 8) ((bf16*)Cout)[(size_t)row * ldc + col] = (bf16)v;
                else         ((float*)Cout)[(size_t)row * ldc + col] = v;
            }
        }
    }
}

// ---- BM=32 GEMM + bias + residual + LayerNorm (in-place Xf, bf16 copy Xb).
//      smem needs 74752 B. ----
__device__ __forceinline__ void bgemm_ln_tile(
        const bf16* __restrict__ A, const bf16* __restrict__ Bt,
        const float* __restrict__ bias, float* __restrict__ Xf,
        const float* __restrict__ lns_, const float* __restrict__ lnb_,
        bf16* __restrict__ Xb, int m0, int K, char* smemc)
{
    bf16* As  = (bf16*)smemc;             // [2][2048]
    bf16* Bs  = (bf16*)(smemc + 8192);    // [2][16384]
    float* ls1 = (float*)(smemc + 73728); // [32][4]
    float* ls2 = ls1 + 128;               // [32][4]
    int tid = threadIdx.x, wid = tid >> 6, lane = tid & 63;
    int lr = lane >> 3, lc = lane & 7, gc = lc ^ lr;
    int cl = lane & 15, ch = lane >> 4;
    int wc = wid;
    f32x4 acc[2][4] = {};
    int nkt = K >> 6;

#define STAGE_LN(kt, buf) { \
    int kb = (kt) << 6; \
    { int row = wid * 8 + lr; \
      GLOAD_LDS16(A + (size_t)(m0 + row) * K + kb + gc * 8, As + (buf) * 2048 + wid * 512); } \
    _Pragma("unroll") \
    for (int s = 0; s < 8; ++s) { \
        int seg = wid * 8 + s; int row = seg * 8 + lr; \
        GLOAD_LDS16(Bt + (size_t)row * K + kb + gc * 8, Bs + (buf) * 16384 + seg * 512); \
    } }

    STAGE_LN(0, 0);
    __syncthreads();
    int cur = 0;
    for (int kt = 0; kt < nkt; ++kt) {
        if (kt + 1 < nkt) STAGE_LN(kt + 1, cur ^ 1);
        #pragma unroll
        for (int kk = 0; kk < 2; ++kk) {
            int c = kk * 4 + ch;
            bf16x8 af[2], bfr[4];
            #pragma unroll
            for (int m = 0; m < 2; ++m) {
                int row = m * 16 + cl;
                af[m] = *(const bf16x8*)(As + cur * 2048 + row * 64 + (c ^ (row & 7)) * 8);
            }
            #pragma unroll
            for (int n = 0; n < 4; ++n) {
                int row = wc * 64 + n * 16 + cl;
                bfr[n] = *(const bf16x8*)(Bs + cur * 16384 + row * 64 + (c ^ (row & 7)) * 8);
            }
            #pragma unroll
            for (int m = 0; m < 2; ++m)
                #pragma unroll
                for (int n = 0; n < 4; ++n)
                    acc[m][n] = __builtin_amdgcn_mfma_f32_16x16x32_bf16(af[m], bfr[n], acc[m][n], 0, 0, 0);
        }
        __syncthreads();
        cur ^= 1;
    }
#undef STAGE_LN
    #pragma unroll
    for (int m = 0; m < 2; ++m) {
        #pragma unroll
        for (int j = 0; j < 4; ++j) {
            int rl = m * 16 + ch * 4 + j;
            float s1 = 0.f, s2 = 0.f;
            #pragma unroll
            for (int n = 0; n < 4; ++n) {
                int col = wc * 64 + n * 16 + cl;
                float v = acc[m][n][j] + bias[col] + Xf[(size_t)(m0 + rl) * 256 + col];
                acc[m][n][j] = v;
                s1 += v; s2 += v * v;
            }
            s1 += __shfl_xor(s1, 1); s2 += __shfl_xor(s2, 1);
            s1 += __shfl_xor(s1, 2); s2 += __shfl_xor(s2, 2);
            s1 += __shfl_xor(s1, 4); s2 += __shfl_xor(s2, 4);
            s1 += __shfl_xor(s1, 8); s2 += __shfl_xor(s2, 8);
            if (cl == 0) { ls1[rl * 4 + wc] = s1; ls2[rl * 4 + wc] = s2; }
        }
    }
    __syncthreads();
    #pragma unroll
    for (int m = 0; m < 2; ++m) {
        #pragma unroll
        for (int j = 0; j < 4; ++j) {
            int rl = m * 16 + ch * 4 + j;
            float su = ls1[rl*4+0] + ls1[rl*4+1] + ls1[rl*4+2] + ls1[rl*4+3];
            float sq = ls2[rl*4+0] + ls2[rl*4+1] + ls2[rl*4+2] + ls2[rl*4+3];
            float mean = su * (1.f / 256.f);
            float var  = sq * (1.f / 256.f) - mean * mean;
            float rstd = rsqrtf(var + 1e-5f);
            #pragma unroll
            for (int n = 0; n < 4; ++n) {
                int col = wc * 64 + n * 16 + cl;
                float r = (acc[m][n][j] - mean) * rstd * lns_[col] + lnb_[col];
                size_t g = (size_t)(m0 + rl) * 256 + col;
                Xf[g] = r;
                Xb[g] = (bf16)r;
            }
        }
    }
    __syncthreads();   // ls reuse safety for persistent loop
}

// ---- 1-wave MFMA attention unit (seq, head). VT/PT: per-wave 9216 B each. ----
template<bool WCA>
__device__ __forceinline__ void mattn_unit(
        int seq, int head, const bf16* __restrict__ Qb, const bf16* __restrict__ Kb,
        const bf16* __restrict__ Vb, const float* __restrict__ maskb,
        bf16* __restrict__ O, short* VT, short* PT, int lane)
{
    const int qstr = WCA ? 256 : 768;
    const int kstr = WCA ? 512 : 768;
    int cl = lane & 15, ch = lane >> 4;
    const bf16* Qp = Qb + (size_t)seq * 64 * qstr + head * 64;
    int kvseq = WCA ? (seq >> 4) : seq;
    const bf16* Kp = Kb + (size_t)kvseq * 64 * kstr + head * 64;
    const bf16* Vp = Vb + (size_t)kvseq * 64 * kstr + head * 64;

    bf16x8 aq[4][2], bk[4][2], vr[4][2];
    #pragma unroll
    for (int t = 0; t < 4; ++t)
        #pragma unroll
        for (int kk = 0; kk < 2; ++kk) {
            int row = t * 16 + cl, d0 = kk * 32 + ch * 8;
            aq[t][kk] = *(const bf16x8*)(Qp + (size_t)row * qstr + d0);
            bk[t][kk] = *(const bf16x8*)(Kp + (size_t)row * kstr + d0);
            vr[t][kk] = *(const bf16x8*)(Vp + (size_t)row * kstr + d0);
        }
    f32x4 sa[4][4] = {};
    #pragma unroll
    for (int kk = 0; kk < 2; ++kk)
        #pragma unroll
        for (int m = 0; m < 4; ++m)
            #pragma unroll
            for (int n = 0; n < 4; ++n)
                sa[m][n] = __builtin_amdgcn_mfma_f32_16x16x32_bf16(aq[m][kk], bk[n][kk], sa[m][n], 0, 0, 0);
    #pragma unroll
    for (int t = 0; t < 4; ++t)
        #pragma unroll
        for (int kk = 0; kk < 2; ++kk) {
            int k = t * 16 + cl, d0 = kk * 32 + ch * 8;
            #pragma unroll
            for (int e = 0; e < 8; ++e)
                VT[(d0 + e) * 72 + k] = vr[t][kk][e];
        }
    float mk4[4];
    if (!WCA) {
        #pragma unroll
        for (int n = 0; n < 4; ++n) mk4[n] = maskb[seq * 64 + n * 16 + cl];
    }
    #pragma unroll
    for (int m = 0; m < 4; ++m) {
        #pragma unroll
        for (int j = 0; j < 4; ++j) {
            int q = m * 16 + ch * 4 + j;
            float rm = -INFINITY;
            #pragma unroll
            for (int n = 0; n < 4; ++n) {
                int k = n * 16 + cl;
                float msk = WCA ? ((abs(q - k) <= 4) ? 0.f : -INFINITY) : mk4[n];
                float v = sa[m][n][j] * 0.125f + msk;
                sa[m][n][j] = v;
                rm = fmaxf(rm, v);
            }
            rm = fmaxf(rm, __shfl_xor(rm, 1));
            rm = fmaxf(rm, __shfl_xor(rm, 2));
            rm = fmaxf(rm, __shfl_xor(rm, 4));
            rm = fmaxf(rm, __shfl_xor(rm, 8));
            float rs = 0.f;
            #pragma unroll
            for (int n = 0; n < 4; ++n) {
                float e = expf(sa[m][n][j] - rm);
                sa[m][n][j] = e;
                rs += e;
            }
            rs += __shfl_xor(rs, 1);
            rs += __shfl_xor(rs, 2);
            rs += __shfl_xor(rs, 4);
            rs += __shfl_xor(rs, 8);
            float inv = 1.f / rs;
            #pragma unroll
            for (int n = 0; n < 4; ++n)
                PT[q * 72 + n * 16 + cl] = f2bf(sa[m][n][j] * inv);
        }
    }
    __syncthreads();
    f32x4 oa[4][4] = {};
    #pragma unroll
    for (int kk = 0; kk < 2; ++kk) {
        bf16x8 av[4], bp[4];
        #pragma unroll
        for (int dm = 0; dm < 4; ++dm)
            av[dm] = *(const bf16x8*)(VT + (dm * 16 + cl) * 72 + kk * 32 + ch * 8);
        #pragma unroll
        for (int qn = 0; qn < 4; ++qn)
            bp[qn] = *(const bf16x8*)(PT + (qn * 16 + cl) * 72 + kk * 32 + ch * 8);
        #pragma unroll
        for (int dm = 0; dm < 4; ++dm)
            #pragma unroll
            for (int qn = 0; qn < 4; ++qn)
                oa[dm][qn] = __builtin_amdgcn_mfma_f32_16x16x32_bf16(av[dm], bp[qn], oa[dm][qn], 0, 0, 0);
    }
    __syncthreads();
    #pragma unroll
    for (int dm = 0; dm < 4; ++dm)
        #pragma unroll
        for (int qn = 0; qn < 4; ++qn)
            #pragma unroll
            for (int j = 0; j < 4; ++j)
                PT[(qn * 16 + cl) * 72 + dm * 16 + ch * 4 + j] = f2bf(oa[dm][qn][j]);
    __syncthreads();
    #pragma unroll
    for (int it = 0; it < 8; ++it) {
        int chunk = it * 64 + lane;
        int tok = chunk >> 3, d0 = (chunk & 7) * 8;
        bf16x8 v = *(const bf16x8*)(PT + tok * 72 + d0);
        *(bf16x8*)(O + ((size_t)seq * 64 + tok) * 256 + head * 64 + d0) = v;
    }
}

// ---- fuse unit: one token row ----
__device__ __forceinline__ void fuse_unit(const MegaArgs& a, int u, int d) {
    int seq = u >> 6, s = u & 63;
    int idx, b;
    if (seq < 128) { b = seq >> 4; idx = a.hist[(size_t)seq * S_N + s]; }
    else           { b = seq - 128; idx = a.cur[b * S_N + s]; }
    float t = a.temp[s * DM + d];
    float v;
    if (idx == C_N) v = a.nullE[d] + t;
    else {
        v = ((d < DIMN) ? a.emb[(size_t)idx * DIMN + d]
                        : fmaxf(a.Eg[((size_t)b * C_N + idx) * DIMN + (d - DIMN)], 0.f)) + t;
    }
    size_t o = (size_t)u * DM + d;
    a.Xenc[o] = v;
    a.Xbf[o]  = (bf16)v;
    if (d == 0) a.maskb[u] = (idx == C_N) ? -INFINITY : 0.f;
}

// ---- initX unit: 1024 consecutive floats of Eg ----
__device__ __forceinline__ void initx_unit(const MegaArgs& a, int u, int tid) {
    int i0 = u * 1024 + tid * 4;
    int k = i0 & 127; int bc = i0 >> 7; int c = bc % C_N; int b = bc / C_N;
    float dd2 = 1.f + a.dvec[b * C_N + c];
    float4 y = *(const float4*)(a.Y + (size_t)c * DIMN + k);
    float4 o = { dd2 * y.x + a.gcn_b[k],     dd2 * y.y + a.gcn_b[k + 1],
                 dd2 * y.z + a.gcn_b[k + 2], dd2 * y.w + a.gcn_b[k + 3] };
    *(float4*)(a.Eg + i0) = o;
}

// ---- edge unit: 2 edges (128 threads each) ----
__device__ __forceinline__ void edge_unit(const MegaArgs& a, int u, int tid) {
    int e = u * 2 + (tid >> 7); int k = tid & 127;
    int s = e % (S_N-1); int bh = e / (S_N-1); int h = bh % HT; int b = bh / HT;
    const int* row = a.hist + (size_t)bh * S_N;
    int src = row[s], dst = row[s+1];
    if (src == C_N || dst == C_N || src == dst) return;
    float w = (1.f + expf(-0.01f * (float)(HT - 1 - h)))
            * sqrtf(1.f + a.dvec[b*C_N+src]) * sqrtf(1.f + a.dvec[b*C_N+dst]);
    atomicAdd(&a.Eg[((size_t)b * C_N + src) * DIMN + k], w * a.Y[(size_t)dst * DIMN + k]);
}

// ---- colsum unit (256 edges) ----
__device__ __forceinline__ void colsum_unit(const MegaArgs& a, int u, int tid) {
    int e = u * 256 + tid;
    if (e >= NEDGE) return;
    int s = e % (S_N-1); int bh = e / (S_N-1); int h = bh % HT; int b = bh / HT;
    const int* row = a.hist + (size_t)bh * S_N;
    int src = row[s], dst = row[s+1];
    if (src != C_N && dst != C_N && src != dst) {
        float w = 1.f + expf(-0.01f * (float)(HT - 1 - h));
        atomicAdd(&a.dvec[b * C_N + dst], w);
    }
}

// ---- agg + ial fused: one (b,s) row -> finalb bf16 ----
__device__ __forceinline__ void agg_ial_unit(int u, const float* __restrict__ SE,
        const float* __restrict__ mc, const bf16* __restrict__ ialw,
        const float* __restrict__ ialb, bf16* __restrict__ finalb, char* smemc)
{
    float* red  = (float*)smemc;          // [4][16]
    float* aggs = (float*)(smemc + 256);  // [256]
    int b = u >> 6, s = u & 63;
    int d = threadIdx.x;
    float mcv = mc[((size_t)b * S_N + s) * DM + d];
    float wv[16], p[16];
    #pragma unroll
    for (int h = 0; h < 16; ++h) {
        wv[h] = SE[(((size_t)(b * HT + h)) * S_N + s) * DM + d];
        p[h] = wv[h] * mcv;
    }
    #pragma unroll
    for (int o = 1; o < 64; o <<= 1)
        #pragma unroll
        for (int h = 0; h < 16; ++h) p[h] += __shfl_xor(p[h], o);
    if ((d & 63) == 0) {
        int w = d >> 6;
        #pragma unroll
        for (int h = 0; h < 16; ++h) red[w * 16 + h] = p[h];
    }
    __syncthreads();
    float sc[16], mx = -INFINITY;
    #pragma unroll
    for (int h = 0; h < 16; ++h) {
        sc[h] = (red[h] + red[16 + h] + red[32 + h] + red[48 + h]) * (1.f / 16.f);
        mx = fmaxf(mx, sc[h]);
    }
    float e[16], sum = 0.f;
    #pragma unroll
    for (int h = 0; h < 16; ++h) { e[h] = expf(sc[h] - mx); sum += e[h]; }
    float inv = 1.f / sum;
    float acc = 0.f;
    #pragma unroll
    for (int h = 0; h < 16; ++h) acc += e[h] * inv * wv[h];
    aggs[d] = acc + mcv;
    __syncthreads();
    if (d < 128) {
        float sumo = ialb[d];
        #pragma unroll 8
        for (int k = 0; k < 256; ++k) sumo += aggs[k] * (float)ialw[d * 256 + k];
        finalb[(size_t)u * 128 + d] = (bf16)fmaxf(sumo, 0.f);
    }
    __syncthreads();   // aggs reuse safety
}

// ---- prep unit dispatcher (transp/tobf/temp + mega-only zero jobs) ----
__device__ __forceinline__ void prep_unit(const MegaArgs& a, int u, int tid, char* smemc) {
    if (u < 1840) {
        const float* s; bf16* d; int K, N, t0;
        if      (u < 512)  { s = a.w_aw;  d = a.wbf_aw;  K = 256;  N = 256;  t0 = u; }
        else if (u < 1024) { s = a.w_fw1; d = a.wbf_fw1; K = 256;  N = 1024; t0 = u - 512; }
        else if (u < 1536) { s = a.w_fw2; d = a.wbf_fw2; K = 1024; N = 256;  t0 = u - 1024; }
        else if (u < 1792) { s = a.w_wca; d = a.wbf_wca; K = 256;  N = 256;  t0 = u - 1536; }
        else if (u < 1808) { s = a.w_gcn; d = a.wbf_gcn; K = 128;  N = 128;  t0 = u - 1792; }
        else               { s = a.w_ial; d = a.wbf_ial; K = 256;  N = 128;  t0 = u - 1808; }
        transp_unit(s, d, K, N, t0, (float(*)[33])smemc);
    } else if (u < 2090) {
        int i = ((u - 1840) * 256 + tid) * 4;
        float4 v = *(const float4*)(a.emb + i);
        a.embbf[i] = (bf16)v.x; a.embbf[i+1] = (bf16)v.y;
        a.embbf[i+2] = (bf16)v.z; a.embbf[i+3] = (bf16)v.w;
    } else if (u < 2154) {
        int s = u - 2090; int d = tid;
        int k = d >> 1;
        float den = powf(10000.f, (2.f * (float)k) / 256.f);
        float arg = (float)s / den;
        a.temp[s * DM + d] = (d & 1) ? cosf(arg) : sinf(arg);
    } else if (u < 2170) {
        int i4 = (u - 2154) * 256 + tid;
        if (i4 < 4000) { float4 z = {0,0,0,0}; *(float4*)(a.dvec + i4 * 4) = z; }
    } else {
        int* p = (int*)(a.embbf + 2000 * 128);
        for (int j = tid; j < 3072; j += 256) p[j] = 0;
    }
}

// =================== cooperative mega-kernel ===================

__global__ __launch_bounds__(256, 2) void k_mega(MegaArgs a) {
    cg::grid_group grid = cg::this_grid();
    __shared__ __align__(16) char smem[74752];
    const int nb = gridDim.x, bid = blockIdx.x;
    const int tid = threadIdx.x, wid = tid >> 6, lane = tid & 63;

    // P0: weight pack + emb->bf16 + temp + zeroing
    for (int u = bid; u < 2171; u += nb) prep_unit(a, u, tid, smem);
    grid.sync();
    // P1: Y = embbf @ gcn_w  +  colsum
    for (int u = bid; u < 48; u += nb) {
        if (u < 16) bgemm2_tile<0>(a.embbf, a.wbf_gcn, nullptr, nullptr, a.Y,
                                   u * 128, 0, 128, 128, 0, smem);
        else colsum_unit(a, u - 16, tid);
    }
    grid.sync();
    // P2: Eg base
    for (int u = bid; u < 2000; u += nb) initx_unit(a, u, tid);
    grid.sync();
    // P3: edge scatter
    for (int u = bid; u < 4032; u += nb) edge_unit(a, u, tid);
    grid.sync();
    // P4: fuse
    for (int u = bid; u < 8704; u += nb) fuse_unit(a, u, tid);
    grid.sync();
    // encoder layers
    for (int l = 0; l < 2; ++l) {
        const bf16* wqkv = a.wbf_aw + l * 262144;
        const float* bl = a.ab + l * 1024;
        for (int u = bid; u < 408; u += nb)
            bgemm2_tile<9>(a.Xbf, wqkv, bl, nullptr, a.QKV,
                           (u / 6) * 128, (u % 6) * 128, 256, 768, 0, smem);
        grid.sync();
        for (int u = bid; u < 136; u += nb)
            mattn_unit<false>(u, wid, a.QKV, a.QKV + 256, a.QKV + 512, a.maskb, a.Abf,
                              (short*)(smem + wid * 18432), (short*)(smem + wid * 18432 + 9216), lane);
        grid.sync();
        for (int u = bid; u < 272; u += nb)
            bgemm_ln_tile(a.Abf, wqkv + 196608, bl + 768, a.Xenc,
                          a.lns + (l * 2) * DM, a.lnb + (l * 2) * DM, a.Xbf, u * 32, 256, smem);
        grid.sync();
        for (int u = bid; u < 544; u += nb)
            bgemm2_tile<11>(a.Xbf, a.wbf_fw1 + l * 262144, a.fb1 + l * DFF, nullptr, a.Hbf,
                            (u / 8) * 128, (u % 8) * 128, 256, DFF, 0, smem);
        grid.sync();
        for (int u = bid; u < 272; u += nb)
            bgemm_ln_tile(a.Hbf, a.wbf_fw2 + l * 262144, a.fb2 + l * DM, a.Xenc,
                          a.lns + (l * 2 + 1) * DM, a.lnb + (l * 2 + 1) * DM, a.Xbf, u * 32, 1024, smem);
        grid.sync();
    }
    // WCA
    for (int u = bid; u < 144; u += nb) {
        if (u < 128)
            bgemm2_tile<9>(a.Xbf, a.wbf_wca, a.wca_b, nullptr, a.QKV,
                           (u >> 1) * 128, (u & 1) * 128, 256, 256, 0, smem);
        else {
            int v = u - 128;
            bgemm2_tile<9>(a.Xbf + (size_t)128 * S_N * DM, a.wbf_wca + 65536, a.wca_b + 256,
                           nullptr, a.QKV + 4194304, (v >> 2) * 128, (v & 3) * 128, 256, 512, 0, smem);
        }
    }
    grid.sync();
    for (int u = bid; u < 128; u += nb)
        mattn_unit<true>(u, wid, a.QKV, a.QKV + 4194304, a.QKV + 4194304 + 256, nullptr, a.Abf,
                         (short*)(smem + wid * 18432), (short*)(smem + wid * 18432 + 9216), lane);
    grid.sync();
    for (int u = bid; u < 128; u += nb)
        bgemm2_tile<5>(a.Abf, a.wbf_wca + 196608, a.wca_b + 768, a.Xenc, a.SE,
                       (u >> 1) * 128, (u & 1) * 128, 256, 256, 0, smem);
    grid.sync();
    for (int u = bid; u < 512; u += nb)
        agg_ial_unit(u, a.SE, a.Xenc + (size_t)128 * S_N * DM, a.wbf_ial, a.ial_b, a.finalb, smem);
    grid.sync();
    for (int u = bid; u < 64; u += nb)
        bgemm2_tile<16>(a.finalb, a.embbf, nullptr, nullptr, a.out,
                        (u >> 4) * 128, (u & 15) * 128, 128, C_N, C_N, smem);
}

// =================== legacy fallback kernels (same bodies) ===================

__global__ void k_prepg(MegaArgs a) {   // 1840 + 250 + 32 + 64 = 2186 blocks
    __shared__ __align__(16) char sm[4352];
    int id = blockIdx.x, tid = threadIdx.x;
    if (id < 1840) { prep_unit(a, id, tid, sm); return; }
    id -= 1840;
    if (id < 250) { prep_unit(a, 1840 + id, tid, sm); return; }
    id -= 250;
    if (id < 32) { colsum_unit(a, id, tid); return; }
    id -= 32;
    prep_unit(a, 2090 + id, tid, sm);   // temp rows
}

__global__ void k_initXg(MegaArgs a) { initx_unit(a, blockIdx.x, threadIdx.x); }
__global__ void k_edgeXg(MegaArgs a) { edge_unit(a, blockIdx.x, threadIdx.x); }
__global__ void k_fuseg(MegaArgs a)  { fuse_unit(a, blockIdx.x, threadIdx.x); }

template<int EPI>
__global__ __launch_bounds__(256) void k_bgemm2g(
        const bf16* A, const bf16* Bt, const float* bias, const float* resid,
        void* C, int K, int ldc, int nreal) {
    __shared__ __align__(16) char sm[65536];
    bgemm2_tile<EPI>(A, Bt, bias, resid, C, blockIdx.y * 128, blockIdx.x * 128, K, ldc, nreal, sm);
}

__global__ __launch_bounds__(256) void k_wcaqkvg(
        const bf16* Xbf, const bf16* mcbf, const bf16* w, const float* wb,
        bf16* Q, bf16* KV) {
    __shared__ __align__(16) char sm[65536];
    int u = blockIdx.x;
    if (u < 128) bgemm2_tile<9>(Xbf, w, wb, nullptr, Q, (u >> 1) * 128, (u & 1) * 128, 256, 256, 0, sm);
    else { int v = u - 128;
           bgemm2_tile<9>(mcbf, w + 65536, wb + 256, nullptr, KV, (v >> 2) * 128, (v & 3) * 128, 256, 512, 0, sm); }
}

__global__ __launch_bounds__(256) void k_bgemm_lng(
        const bf16* A, const bf16* Bt, const float* bias, float* Xf,
        const float* lns_, const float* lnb_, bf16* Xb, int K) {
    __shared__ __align__(16) char sm[74752];
    bgemm_ln_tile(A, Bt, bias, Xf, lns_, lnb_, Xb, blockIdx.x * 32, K, sm);
}

template<bool WCA>
__global__ __launch_bounds__(64) void k_mattng(
        const bf16* Qb, const bf16* Kb, const bf16* Vb, const float* maskb, bf16* O) {
    __shared__ __align__(16) char sm[18432];
    mattn_unit<WCA>(blockIdx.x >> 2, blockIdx.x & 3, Qb, Kb, Vb, maskb, O,
                    (short*)sm, (short*)(sm + 9216), threadIdx.x);
}

__global__ __launch_bounds__(256) void k_aggialg(
        const float* SE, const float* mc, const bf16* ialw, const float* ialb, bf16* finalb) {
    __shared__ __align__(16) char sm[2048];
    agg_ial_unit(blockIdx.x, SE, mc, ialw, ialb, finalb, sm);
}

// =================== launch ===================

extern "C" void kernel_launch(void* const* d_in, const int* in_sizes, int n_in,
                              void* d_out, int out_size, void* d_ws, size_t ws_size,
                              hipStream_t stream) {
    float* ws = (float*)d_ws;

    // ---- arena (float offsets) ----
    float* dvec   = ws + 0;
    float* maskb  = ws + 16000;
    float* temp   = ws + 24704;
    bf16*  finalb = (bf16*)(ws + 106624);
    bf16*  embbf  = (bf16*)(ws + 139392);        // 2048x128 padded
    float* Y      = ws + 270464;
    float* Eg     = ws + 532608;
    bf16*  wbf    = (bf16*)(ws + 2580608);
    float* Xenc   = ws + 3522688;
    bf16*  Xbf    = (bf16*)(ws + 5750912);
    bf16*  Hbf    = (bf16*)(ws + 6865024);       // 8,912,896 bf16; Abf aliases its head
    bf16*  QKVbf  = (bf16*)(ws + 11321472);
    float* SE     = ws + 14663808;

    MegaArgs a;
    a.hist  = (const int*)d_in[0];   a.cur   = (const int*)d_in[1];
    a.emb   = (const float*)d_in[2]; a.nullE = (const float*)d_in[3];
    a.w_gcn = (const float*)d_in[4]; a.gcn_b = (const float*)d_in[5];
    a.w_aw  = (const float*)d_in[6]; a.ab    = (const float*)d_in[7];
    a.w_fw1 = (const float*)d_in[8]; a.fb1   = (const float*)d_in[9];
    a.w_fw2 = (const float*)d_in[10]; a.fb2  = (const float*)d_in[11];
    a.lns   = (const float*)d_in[12]; a.lnb  = (const float*)d_in[13];
    a.w_wca = (const float*)d_in[14]; a.wca_b = (const float*)d_in[15];
    a.w_ial = (const float*)d_in[16]; a.ial_b = (const float*)d_in[17];
    a.dvec = dvec; a.maskb = maskb; a.temp = temp; a.Y = Y; a.Eg = Eg;
    a.Xenc = Xenc; a.SE = SE; a.out = (float*)d_out;
    a.embbf = embbf;
    a.wbf_aw = wbf; a.wbf_fw1 = wbf + 524288; a.wbf_fw2 = wbf + 1048576;
    a.wbf_wca = wbf + 1572864; a.wbf_gcn = wbf + 1835008; a.wbf_ial = wbf + 1851392;
    a.Xbf = Xbf; a.Abf = Hbf; a.Hbf = Hbf; a.QKV = QKVbf; a.finalb = finalb;

    // ---- cooperative mega-kernel path ----
    hipError_t st = hipErrorNotSupported;
    int dev = 0; hipGetDevice(&dev);
    int coop = 0; hipDeviceGetAttribute(&coop, hipDeviceAttributeCooperativeLaunch, dev);
    if (coop) {
        int occ = 0;
        hipOccupancyMaxActiveBlocksPerMultiprocessor(&occ, (const void*)k_mega, 256, 0);
        int nblk = (occ > 0 ? occ : 1) * 256;
        if (nblk > 512) nblk = 512;
        void* params[] = { (void*)&a };
        st = hipLaunchCooperativeKernel((const void*)k_mega, dim3(nblk), dim3(256),
                                        params, 0, stream);
    }
    if (st == hipSuccess) return;

    // ---- fallback: validated multi-kernel sequence (same bodies) ----
    hipMemsetAsync(dvec, 0, 16000 * sizeof(float), stream);
    hipMemsetAsync(embbf + 2000 * 128, 0, 48 * 128 * sizeof(bf16), stream);
    k_prepg<<<2186, 256, 0, stream>>>(a);
    k_bgemm2g<0><<<dim3(1, 16), 256, 0, stream>>>(embbf, a.wbf_gcn, nullptr, nullptr, Y, 128, 128, 0);
    k_initXg<<<2000, 256, 0, stream>>>(a);
    k_edgeXg<<<4032, 256, 0, stream>>>(a);
    k_fuseg<<<8704, 256, 0, stream>>>(a);
    for (int l = 0; l < 2; ++l) {
        const bf16* wqkv = a.wbf_aw + l * 262144;
        const float* bl = a.ab + l * 1024;
        k_bgemm2g<9><<<dim3(6, 68), 256, 0, stream>>>(Xbf, wqkv, bl, nullptr, QKVbf, 256, 768, 0);
        k_mattng<false><<<544, 64, 0, stream>>>(QKVbf, QKVbf + 256, QKVbf + 512, maskb, a.Abf);
        k_bgemm_lng<<<272, 256, 0, stream>>>(a.Abf, wqkv + 196608, bl + 768, Xenc,
                a.lns + (l * 2) * DM, a.lnb + (l * 2) * DM, Xbf, 256);
        k_bgemm2g<11><<<dim3(8, 68), 256, 0, stream>>>(Xbf, a.wbf_fw1 + l * 262144,
                a.fb1 + l * DFF, nullptr, Hbf, 256, DFF, 0);
        k_bgemm_lng<<<272, 256, 0, stream>>>(Hbf, a.wbf_fw2 + l * 262144, a.fb2 + l * DM, Xenc,
                a.lns + (l * 2 + 1) * DM, a.lnb + (l * 2 + 1) * DM, Xbf, 1024);
    }
    bf16* mc_bf = Xbf + (size_t)128 * S_N * DM;
    k_wcaqkvg<<<144, 256, 0, stream>>>(Xbf, mc_bf, a.wbf_wca, a.wca_b, QKVbf, QKVbf + 4194304);
    k_mattng<true><<<512, 64, 0, stream>>>(QKVbf, QKVbf + 4194304, QKVbf + 4194304 + 256,
                                           nullptr, a.Abf);
    k_bgemm2g<5><<<dim3(2, 64), 256, 0, stream>>>(a.Abf, a.wbf_wca + 196608, a.wca_b + 768,
                                                  Xenc, SE, 256, 256, 0);
    k_aggialg<<<512, 256, 0, stream>>>(SE, Xenc + (size_t)128 * S_N * DM, a.wbf_ial, a.ial_b, finalb);
    k_bgemm2g<16><<<dim3(16, 4), 256, 0, stream>>>(finalb, embbf, nullptr, nullptr,
                                                   (float*)d_out, 128, C_N, C_N);
}

// Round 13
// 317.699 us; speedup vs baseline: 3.2660x; 3.2660x over previous
//
#include <hip/hip_runtime.h>
#include <hip/hip_bf16.h>
#include <math.h>

#define C_N   2000
#define DIMN  128
#define DM    256
#define B_N   8
#define HT    16
#define S_N   64
#define NSEQ  136
#define DFF   1024
#define NEDGE (B_N*HT*(S_N-1))   // 8064

typedef __hip_bfloat16 bf16;
typedef short bf16x8 __attribute__((ext_vector_type(8)));
typedef float f32x4  __attribute__((ext_vector_type(4)));

#define GLOAD_LDS16(gp, lp) \
    __builtin_amdgcn_global_load_lds((const __attribute__((address_space(1))) void*)(gp), \
                                     (__attribute__((address_space(3))) void*)(lp), 16, 0, 0)

__device__ __forceinline__ short f2bf(float v) {
    bf16 t = (bf16)v;
    return *reinterpret_cast<short*>(&t);
}

// ---------------- fused prologue: weight transpose + emb->bf16 + colsum + temp ----------------
struct TEnt { const float* s; bf16* d; int K; int N; int nm; int tiles; };
struct PrepArgs {
    TEnt e[6];                       // 1840 tiles
    const float* emb; bf16* embbf;   // 250 blocks
    const int* hist; float* colsum;  // 32 blocks
    float* temp;                     // 64 blocks
};

__global__ void k_prep(PrepArgs p) {
    int id = blockIdx.x;
    int t = threadIdx.y * 32 + threadIdx.x;
    if (id < 1840) {                 // ---- weight transpose tiles ----
        __shared__ float tl[32][33];
        TEnt en = p.e[0];
        #pragma unroll
        for (int k = 0; k < 6; ++k) {
            if (id < p.e[k].tiles) { en = p.e[k]; break; }
            id -= p.e[k].tiles;
        }
        int tn = en.N >> 5;
        int per = (en.K >> 5) * tn;
        int mat = id / per, t2 = id % per;
        int ty = t2 / tn, tx = t2 % tn;
        const float* s = en.s + (size_t)mat * en.K * en.N;
        bf16* d = en.d + (size_t)mat * en.N * en.K;
        int k0 = ty * 32, n0 = tx * 32;
        #pragma unroll
        for (int j = 0; j < 32; j += 8)
            tl[threadIdx.y + j][threadIdx.x] = s[(size_t)(k0 + threadIdx.y + j) * en.N + n0 + threadIdx.x];
        __syncthreads();
        #pragma unroll
        for (int j = 0; j < 32; j += 8)
            d[(size_t)(n0 + threadIdx.y + j) * en.K + k0 + threadIdx.x] = (bf16)tl[threadIdx.x][threadIdx.y + j];
        return;
    }
    id -= 1840;
    if (id < 250) {                  // ---- emb -> bf16 ----
        int i = (id * 256 + t) * 4;
        float4 v = *(const float4*)(p.emb + i);
        p.embbf[i]   = (bf16)v.x; p.embbf[i+1] = (bf16)v.y;
        p.embbf[i+2] = (bf16)v.z; p.embbf[i+3] = (bf16)v.w;
        return;
    }
    id -= 250;
    if (id < 32) {                   // ---- colsum ----
        int e = id * 256 + t;
        if (e >= NEDGE) return;
        int s = e % (S_N-1); int bh = e / (S_N-1); int h = bh % HT; int b = bh / HT;
        const int* row = p.hist + (size_t)bh * S_N;
        int src = row[s], dst = row[s+1];
        if (src != C_N && dst != C_N && src != dst) {
            float w = 1.f + expf(-0.01f * (float)(HT - 1 - h));
            atomicAdd(&p.colsum[b * C_N + dst], w);
        }
        return;
    }
    id -= 32;
    {                                // ---- temporal table ----
        int s = id; int d = t;
        int k = d >> 1;
        float den = powf(10000.f, (2.f * (float)k) / 256.f);
        float arg = (float)s / den;
        p.temp[s * DM + d] = (d & 1) ? cosf(arg) : sinf(arg);
    }
}

// ---------------- edge scatter: EgE += w * Y[dst]  (EgE pre-zeroed) ----------------
// 4032 blocks x 256 threads, 2 edges per block
__global__ void k_edgeX(const int* __restrict__ hist, const float* __restrict__ cs,
                        const float* __restrict__ Y, float* __restrict__ EgE) {
    int tid = threadIdx.x;
    int e = blockIdx.x * 2 + (tid >> 7); int k = tid & 127;
    int s = e % (S_N-1); int bh = e / (S_N-1); int h = bh % HT; int b = bh / HT;
    const int* row = hist + (size_t)bh * S_N;
    int src = row[s], dst = row[s+1];
    if (src == C_N || dst == C_N || src == dst) return;
    float w = (1.f + expf(-0.01f * (float)(HT - 1 - h)))
            * sqrtf(1.f + cs[b*C_N+src]) * sqrtf(1.f + cs[b*C_N+dst]);
    atomicAdd(&EgE[((size_t)b * C_N + src) * DIMN + k], w * Y[(size_t)dst * DIMN + k]);
}

// ---------------- fuse (GCN base term computed inline; relu folded) ----------------
__global__ void k_fuse2(const int* __restrict__ hist, const int* __restrict__ cur,
                        const float* __restrict__ E, const float* __restrict__ cs,
                        const float* __restrict__ Y, const float* __restrict__ gb,
                        const float* __restrict__ EgE, const float* __restrict__ nullE,
                        const float* __restrict__ temp, float* __restrict__ Xenc,
                        bf16* __restrict__ Xbf, float* __restrict__ maskb) {
    int blk = blockIdx.x;           // seq*64 + s
    int seq = blk >> 6, s = blk & 63;
    int d = threadIdx.x;
    int idx, b;
    if (seq < 128) { b = seq >> 4; idx = hist[(size_t)seq * S_N + s]; }
    else           { b = seq - 128; idx = cur[b * S_N + s]; }
    float t = temp[s * DM + d];
    float v;
    if (idx == C_N) v = nullE[d] + t;
    else if (d < DIMN) v = E[(size_t)idx * DIMN + d] + t;
    else {
        int k = d - DIMN;
        float dd2 = 1.f + cs[b * C_N + idx];
        float g = dd2 * Y[(size_t)idx * DIMN + k] + gb[k]
                + EgE[((size_t)b * C_N + idx) * DIMN + k];
        v = fmaxf(g, 0.f) + t;
    }
    size_t o = ((size_t)seq * S_N + s) * DM + d;
    Xenc[o] = v;
    Xbf[o]  = (bf16)v;
    if (d == 0) maskb[seq * S_N + s] = (idx == C_N) ? -INFINITY : 0.f;
}

// ---------------- 128x128 MFMA GEMM (dbuf + prefetch) ----------------
// EPI: 1=bias 2=relu 4=resid(f32,ldc) 8=bf16 out 16=col-mask(col<nreal). K%64==0.
template<int EPI>
__device__ __forceinline__ void bgemm2_body(
        const bf16* __restrict__ A, const bf16* __restrict__ Bt,
        const float* __restrict__ bias, const float* __restrict__ resid,
        void* __restrict__ Cout, int m0, int n0, int K, int ldc, int nreal,
        bf16* __restrict__ As, bf16* __restrict__ Bs)   // [2][8192] each
{
    int tid = threadIdx.x;
    int wid = tid >> 6, lane = tid & 63;
    int wr = wid >> 1, wc = wid & 1;
    int lr = lane >> 3, lc = lane & 7;
    int gc = lc ^ lr;
    f32x4 acc[4][4] = {};
    int nkt = K >> 6;

#define STAGE2(kt, buf) { \
    int kb = (kt) << 6; \
    _Pragma("unroll") \
    for (int s = 0; s < 4; ++s) { \
        int seg = wid * 4 + s; int row = seg * 8 + lr; \
        GLOAD_LDS16(A + (size_t)(m0 + row) * K + kb + gc * 8, As + (buf) * 8192 + seg * 512); \
    } \
    _Pragma("unroll") \
    for (int s = 0; s < 4; ++s) { \
        int seg = wid * 4 + s; int row = seg * 8 + lr; \
        GLOAD_LDS16(Bt + (size_t)(n0 + row) * K + kb + gc * 8, Bs + (buf) * 8192 + seg * 512); \
    } }

    STAGE2(0, 0);
    __syncthreads();
    int cur = 0;
    for (int kt = 0; kt < nkt; ++kt) {
        if (kt + 1 < nkt) STAGE2(kt + 1, cur ^ 1);
        #pragma unroll
        for (int kk = 0; kk < 2; ++kk) {
            bf16x8 af[4], bfr[4];
            int c = kk * 4 + (lane >> 4);
            #pragma unroll
            for (int m = 0; m < 4; ++m) {
                int row = wr * 64 + m * 16 + (lane & 15);
                af[m] = *(const bf16x8*)(As + cur * 8192 + row * 64 + (c ^ (row & 7)) * 8);
            }
            #pragma unroll
            for (int n = 0; n < 4; ++n) {
                int row = wc * 64 + n * 16 + (lane & 15);
                bfr[n] = *(const bf16x8*)(Bs + cur * 8192 + row * 64 + (c ^ (row & 7)) * 8);
            }
            #pragma unroll
            for (int m = 0; m < 4; ++m)
                #pragma unroll
                for (int n = 0; n < 4; ++n)
                    acc[m][n] = __builtin_amdgcn_mfma_f32_16x16x32_bf16(af[m], bfr[n], acc[m][n], 0, 0, 0);
        }
        __syncthreads();
        cur ^= 1;
    }
#undef STAGE2
    int cl = lane & 15, ch = lane >> 4;
    #pragma unroll
    for (int n = 0; n < 4; ++n) {
        int col = n0 + wc * 64 + n * 16 + cl;
        if ((EPI & 16) && col >= nreal) continue;
        float bv = (EPI & 1) ? bias[col] : 0.f;
        #pragma unroll
        for (int m = 0; m < 4; ++m) {
            #pragma unroll
            for (int j = 0; j < 4; ++j) {
                int row = m0 + wr * 64 + m * 16 + ch * 4 + j;
                float v = acc[m][n][j] + bv;
                if (EPI & 4) v += resid[(size_t)row * ldc + col];
                if (EPI & 2) v = fmaxf(v, 0.f);
                if (EPI & 8) ((bf16*)Cout)[(size_t)row * ldc + col] = (bf16)v;
                else         ((float*)Cout)[(size_t)row * ldc + col] = v;
            }
        }
    }
}

template<int EPI>
__global__ __launch_bounds__(256) void k_bgemm2(
        const bf16* __restrict__ A, const bf16* __restrict__ Bt,
        const float* __restrict__ bias, const float* __restrict__ resid,
        void* __restrict__ Cout, int K, int ldc, int nreal)
{
    __shared__ bf16 As[2][8192], Bs[2][8192];
    bgemm2_body<EPI>(A, Bt, bias, resid, Cout, blockIdx.y * 128, blockIdx.x * 128,
                     K, ldc, nreal, &As[0][0], &Bs[0][0]);
}

// WCA Q + KV in one launch: blocks 0..127 -> Q; 128..143 -> KV
__global__ __launch_bounds__(256) void k_wcaqkv(
        const bf16* __restrict__ Xbf, const bf16* __restrict__ mcbf,
        const bf16* __restrict__ wwca, const float* __restrict__ wb,
        bf16* __restrict__ Q, bf16* __restrict__ KV)
{
    __shared__ bf16 As[2][8192], Bs[2][8192];
    int bid = blockIdx.x;
    if (bid < 128)
        bgemm2_body<9>(Xbf, wwca, wb, nullptr, Q, (bid >> 1) * 128, (bid & 1) * 128,
                       256, 256, 0, &As[0][0], &Bs[0][0]);
    else {
        int l = bid - 128;
        bgemm2_body<9>(mcbf, wwca + 65536, wb + 256, nullptr, KV, (l >> 2) * 128, (l & 3) * 128,
                       256, 512, 0, &As[0][0], &Bs[0][0]);
    }
}

// ---------------- BM=32 GEMM + bias + residual + LayerNorm (validated R6) ----------------
__global__ __launch_bounds__(256) void k_bgemm_ln(
        const bf16* __restrict__ A, const bf16* __restrict__ Bt,
        const float* __restrict__ bias, float* __restrict__ Xf,
        const float* __restrict__ lns_, const float* __restrict__ lnb_,
        bf16* __restrict__ Xb, int M, int K)
{
    __shared__ bf16 As[2][32 * 64];
    __shared__ bf16 Bs[2][256 * 64];
    __shared__ float ls1[32][4], ls2[32][4];
    int tid = threadIdx.x, wid = tid >> 6, lane = tid & 63;
    int lr = lane >> 3, lc = lane & 7, gc = lc ^ lr;
    int cl = lane & 15, ch = lane >> 4;
    int m0 = blockIdx.x * 32;
    int wc = wid;
    f32x4 acc[2][4] = {};
    int nkt = K >> 6;

#define STAGE_LN(kt, buf) { \
    int kb = (kt) << 6; \
    { int row = wid * 8 + lr; \
      GLOAD_LDS16(A + (size_t)(m0 + row) * K + kb + gc * 8, &As[buf][wid * 512]); } \
    _Pragma("unroll") \
    for (int s = 0; s < 8; ++s) { \
        int seg = wid * 8 + s; int row = seg * 8 + lr; \
        GLOAD_LDS16(Bt + (size_t)row * K + kb + gc * 8, &Bs[buf][seg * 512]); \
    } }

    STAGE_LN(0, 0);
    __syncthreads();
    int cur = 0;
    for (int kt = 0; kt < nkt; ++kt) {
        if (kt + 1 < nkt) STAGE_LN(kt + 1, cur ^ 1);
        #pragma unroll
        for (int kk = 0; kk < 2; ++kk) {
            int c = kk * 4 + ch;
            bf16x8 af[2], bfr[4];
            #pragma unroll
            for (int m = 0; m < 2; ++m) {
                int row = m * 16 + cl;
                af[m] = *(const bf16x8*)(&As[cur][row * 64 + (c ^ (row & 7)) * 8]);
            }
            #pragma unroll
            for (int n = 0; n < 4; ++n) {
                int row = wc * 64 + n * 16 + cl;
                bfr[n] = *(const bf16x8*)(&Bs[cur][row * 64 + (c ^ (row & 7)) * 8]);
            }
            #pragma unroll
            for (int m = 0; m < 2; ++m)
                #pragma unroll
                for (int n = 0; n < 4; ++n)
                    acc[m][n] = __builtin_amdgcn_mfma_f32_16x16x32_bf16(af[m], bfr[n], acc[m][n], 0, 0, 0);
        }
        __syncthreads();
        cur ^= 1;
    }
#undef STAGE_LN
    #pragma unroll
    for (int m = 0; m < 2; ++m) {
        #pragma unroll
        for (int j = 0; j < 4; ++j) {
            int rl = m * 16 + ch * 4 + j;
            float s1 = 0.f, s2 = 0.f;
            #pragma unroll
            for (int n = 0; n < 4; ++n) {
                int col = wc * 64 + n * 16 + cl;
                float v = acc[m][n][j] + bias[col] + Xf[(size_t)(m0 + rl) * 256 + col];
                acc[m][n][j] = v;
                s1 += v; s2 += v * v;
            }
            s1 += __shfl_xor(s1, 1); s2 += __shfl_xor(s2, 1);
            s1 += __shfl_xor(s1, 2); s2 += __shfl_xor(s2, 2);
            s1 += __shfl_xor(s1, 4); s2 += __shfl_xor(s2, 4);
            s1 += __shfl_xor(s1, 8); s2 += __shfl_xor(s2, 8);
            if (cl == 0) { ls1[rl][wc] = s1; ls2[rl][wc] = s2; }
        }
    }
    __syncthreads();
    #pragma unroll
    for (int m = 0; m < 2; ++m) {
        #pragma unroll
        for (int j = 0; j < 4; ++j) {
            int rl = m * 16 + ch * 4 + j;
            float su = ls1[rl][0] + ls1[rl][1] + ls1[rl][2] + ls1[rl][3];
            float sq = ls2[rl][0] + ls2[rl][1] + ls2[rl][2] + ls2[rl][3];
            float mean = su * (1.f / 256.f);
            float var  = sq * (1.f / 256.f) - mean * mean;
            float rstd = rsqrtf(var + 1e-5f);
            #pragma unroll
            for (int n = 0; n < 4; ++n) {
                int col = wc * 64 + n * 16 + cl;
                float r = (acc[m][n][j] - mean) * rstd * lns_[col] + lnb_[col];
                size_t g = (size_t)(m0 + rl) * 256 + col;
                Xf[g] = r;
                Xb[g] = (bf16)r;
            }
        }
    }
}

// ---------------- 1-wave MFMA attention (validated R6) ----------------
template<bool WCA>
__global__ __launch_bounds__(64) void k_mattn(
        const bf16* __restrict__ Qb, const bf16* __restrict__ Kb,
        const bf16* __restrict__ Vb, const float* __restrict__ maskb,
        bf16* __restrict__ O, int qstr, int kstr)
{
    int seq = blockIdx.x >> 2, head = blockIdx.x & 3;
    int lane = threadIdx.x;
    int cl = lane & 15, ch = lane >> 4;
    __shared__ __align__(16) short VT[64 * 72];
    __shared__ __align__(16) short PT[64 * 72];

    const bf16* Qp = Qb + (size_t)seq * 64 * qstr + head * 64;
    int kvseq = WCA ? (seq >> 4) : seq;
    const bf16* Kp = Kb + (size_t)kvseq * 64 * kstr + head * 64;
    const bf16* Vp = Vb + (size_t)kvseq * 64 * kstr + head * 64;

    bf16x8 aq[4][2], bk[4][2], vr[4][2];
    #pragma unroll
    for (int t = 0; t < 4; ++t)
        #pragma unroll
        for (int kk = 0; kk < 2; ++kk) {
            int row = t * 16 + cl, d0 = kk * 32 + ch * 8;
            aq[t][kk] = *(const bf16x8*)(Qp + (size_t)row * qstr + d0);
            bk[t][kk] = *(const bf16x8*)(Kp + (size_t)row * kstr + d0);
            vr[t][kk] = *(const bf16x8*)(Vp + (size_t)row * kstr + d0);
        }
    f32x4 sa[4][4] = {};
    #pragma unroll
    for (int kk = 0; kk < 2; ++kk)
        #pragma unroll
        for (int m = 0; m < 4; ++m)
            #pragma unroll
            for (int n = 0; n < 4; ++n)
                sa[m][n] = __builtin_amdgcn_mfma_f32_16x16x32_bf16(aq[m][kk], bk[n][kk], sa[m][n], 0, 0, 0);
    #pragma unroll
    for (int t = 0; t < 4; ++t)
        #pragma unroll
        for (int kk = 0; kk < 2; ++kk) {
            int k = t * 16 + cl, d0 = kk * 32 + ch * 8;
            #pragma unroll
            for (int e = 0; e < 8; ++e)
                VT[(d0 + e) * 72 + k] = vr[t][kk][e];
        }
    float mk4[4];
    if (!WCA) {
        #pragma unroll
        for (int n = 0; n < 4; ++n) mk4[n] = maskb[seq * 64 + n * 16 + cl];
    }
    #pragma unroll
    for (int m = 0; m < 4; ++m) {
        #pragma unroll
        for (int j = 0; j < 4; ++j) {
            int q = m * 16 + ch * 4 + j;
            float rm = -INFINITY;
            #pragma unroll
            for (int n = 0; n < 4; ++n) {
                int k = n * 16 + cl;
                float msk = WCA ? ((abs(q - k) <= 4) ? 0.f : -INFINITY) : mk4[n];
                float v = sa[m][n][j] * 0.125f + msk;
                sa[m][n][j] = v;
                rm = fmaxf(rm, v);
            }
            rm = fmaxf(rm, __shfl_xor(rm, 1));
            rm = fmaxf(rm, __shfl_xor(rm, 2));
            rm = fmaxf(rm, __shfl_xor(rm, 4));
            rm = fmaxf(rm, __shfl_xor(rm, 8));
            float rs = 0.f;
            #pragma unroll
            for (int n = 0; n < 4; ++n) {
                float e = expf(sa[m][n][j] - rm);
                sa[m][n][j] = e;
                rs += e;
            }
            rs += __shfl_xor(rs, 1);
            rs += __shfl_xor(rs, 2);
            rs += __shfl_xor(rs, 4);
            rs += __shfl_xor(rs, 8);
            float inv = 1.f / rs;
            #pragma unroll
            for (int n = 0; n < 4; ++n)
                PT[q * 72 + n * 16 + cl] = f2bf(sa[m][n][j] * inv);
        }
    }
    __syncthreads();
    f32x4 oa[4][4] = {};
    #pragma unroll
    for (int kk = 0; kk < 2; ++kk) {
        bf16x8 av[4], bp[4];
        #pragma unroll
        for (int dm = 0; dm < 4; ++dm)
            av[dm] = *(const bf16x8*)(VT + (dm * 16 + cl) * 72 + kk * 32 + ch * 8);
        #pragma unroll
        for (int qn = 0; qn < 4; ++qn)
            bp[qn] = *(const bf16x8*)(PT + (qn * 16 + cl) * 72 + kk * 32 + ch * 8);
        #pragma unroll
        for (int dm = 0; dm < 4; ++dm)
            #pragma unroll
            for (int qn = 0; qn < 4; ++qn)
                oa[dm][qn] = __builtin_amdgcn_mfma_f32_16x16x32_bf16(av[dm], bp[qn], oa[dm][qn], 0, 0, 0);
    }
    __syncthreads();
    #pragma unroll
    for (int dm = 0; dm < 4; ++dm)
        #pragma unroll
        for (int qn = 0; qn < 4; ++qn)
            #pragma unroll
            for (int j = 0; j < 4; ++j)
                PT[(qn * 16 + cl) * 72 + dm * 16 + ch * 4 + j] = f2bf(oa[dm][qn][j]);
    __syncthreads();
    #pragma unroll
    for (int it = 0; it < 8; ++it) {
        int chunk = it * 64 + lane;
        int tok = chunk >> 3, d0 = (chunk & 7) * 8;
        bf16x8 v = *(const bf16x8*)(PT + tok * 72 + d0);
        *(bf16x8*)(O + ((size_t)seq * 64 + tok) * 256 + head * 64 + d0) = v;
    }
}

// ---------------- agg + ial fused (validated in R8 mega) ----------------
__global__ __launch_bounds__(256) void k_aggial(
        const float* __restrict__ SE, const float* __restrict__ mc,
        const bf16* __restrict__ ialw, const float* __restrict__ ialb,
        bf16* __restrict__ finalb)
{
    __shared__ float red[4][16];
    __shared__ float aggs[256];
    int u = blockIdx.x; int b = u >> 6, s = u & 63;
    int d = threadIdx.x;
    float mcv = mc[((size_t)b * S_N + s) * DM + d];
    float wv[16], p[16];
    #pragma unroll
    for (int h = 0; h < 16; ++h) {
        wv[h] = SE[(((size_t)(b * HT + h)) * S_N + s) * DM + d];
        p[h] = wv[h] * mcv;
    }
    #pragma unroll
    for (int o = 1; o < 64; o <<= 1)
        #pragma unroll
        for (int h = 0; h < 16; ++h) p[h] += __shfl_xor(p[h], o);
    if ((d & 63) == 0) {
        int w = d >> 6;
        #pragma unroll
        for (int h = 0; h < 16; ++h) red[w][h] = p[h];
    }
    __syncthreads();
    float sc[16], mx = -INFINITY;
    #pragma unroll
    for (int h = 0; h < 16; ++h) {
        sc[h] = (red[0][h] + red[1][h] + red[2][h] + red[3][h]) * (1.f / 16.f);
        mx = fmaxf(mx, sc[h]);
    }
    float e[16], sum = 0.f;
    #pragma unroll
    for (int h = 0; h < 16; ++h) { e[h] = expf(sc[h] - mx); sum += e[h]; }
    float inv = 1.f / sum;
    float acc = 0.f;
    #pragma unroll
    for (int h = 0; h < 16; ++h) acc += e[h] * inv * wv[h];
    aggs[d] = acc + mcv;
    __syncthreads();
    if (d < 128) {
        float sumo = ialb[d];
        #pragma unroll 8
        for (int k = 0; k < 256; ++k) sumo += aggs[k] * (float)ialw[d * 256 + k];
        finalb[(size_t)u * 128 + d] = (bf16)fmaxf(sumo, 0.f);
    }
}

// ---------------- launch ----------------

extern "C" void kernel_launch(void* const* d_in, const int* in_sizes, int n_in,
                              void* d_out, int out_size, void* d_ws, size_t ws_size,
                              hipStream_t stream) {
    const int*   history = (const int*)d_in[0];
    const int*   cur     = (const int*)d_in[1];
    const float* emb     = (const float*)d_in[2];
    const float* nullE   = (const float*)d_in[3];
    const float* gcn_w   = (const float*)d_in[4];
    const float* gcn_b   = (const float*)d_in[5];
    const float* aw      = (const float*)d_in[6];
    const float* ab      = (const float*)d_in[7];
    const float* fw1     = (const float*)d_in[8];
    const float* fb1     = (const float*)d_in[9];
    const float* fw2     = (const float*)d_in[10];
    const float* fb2     = (const float*)d_in[11];
    const float* lns     = (const float*)d_in[12];
    const float* lnb     = (const float*)d_in[13];
    const float* wca_w   = (const float*)d_in[14];
    const float* wca_b   = (const float*)d_in[15];
    const float* ial_w   = (const float*)d_in[16];
    const float* ial_b   = (const float*)d_in[17];
    float* out = (float*)d_out;
    float* ws  = (float*)d_ws;

    // ---- arena (float offsets) ----
    float* dvec   = ws + 0;            // 16,000 (colsum)
    float* maskb  = ws + 16000;        // 8,704
    float* temp   = ws + 24704;        // 16,384
    bf16*  finalb = (bf16*)(ws + 106624);        // 65,536 bf16 (512x128)
    bf16*  embbf  = (bf16*)(ws + 139392);        // 262,144 bf16 (2048x128 padded)
    float* Y      = ws + 270464;       // 262,144 f32
    float* Eg     = ws + 532608;       // 2,048,000 f32 (edge terms only)
    bf16*  wbf    = (bf16*)(ws + 2580608);       // 1,884,160 bf16
    float* Xenc   = ws + 3522688;      // 2,228,224 f32
    bf16*  Xbf    = (bf16*)(ws + 5750912);       // 2,228,224 bf16
    bf16*  Hbf    = (bf16*)(ws + 6865024);       // 8,912,896 bf16 (Abf aliases head)
    bf16*  QKVbf  = (bf16*)(ws + 11321472);      // 6,684,672 bf16
    float* SE     = ws + 14663808;     // 2,097,152 f32

    bf16* wbf_aw  = wbf;
    bf16* wbf_fw1 = wbf + 524288;
    bf16* wbf_fw2 = wbf + 1048576;
    bf16* wbf_wca = wbf + 1572864;
    bf16* wbf_gcn = wbf + 1835008;
    bf16* wbf_ial = wbf + 1851392;

    bf16* Abf  = Hbf;                  // alias (validated R8 mega)
    bf16* Qwbf = QKVbf;
    bf16* KVbf = QKVbf + 4194304;

    // --- prologue ---
    hipMemsetAsync(dvec, 0, 16000 * sizeof(float), stream);
    hipMemsetAsync(Eg, 0, 2048000 * sizeof(float), stream);
    hipMemsetAsync(embbf + 2000 * 128, 0, 48 * 128 * sizeof(bf16), stream);
    PrepArgs pa;
    pa.e[0] = { aw,    wbf_aw,  256,  256, 8, 512 };
    pa.e[1] = { fw1,   wbf_fw1, 256, 1024, 2, 512 };
    pa.e[2] = { fw2,   wbf_fw2, 1024, 256, 2, 512 };
    pa.e[3] = { wca_w, wbf_wca, 256,  256, 4, 256 };
    pa.e[4] = { gcn_w, wbf_gcn, 128,  128, 1,  16 };
    pa.e[5] = { ial_w, wbf_ial, 256,  128, 1,  32 };
    pa.emb = emb; pa.embbf = embbf;
    pa.hist = history; pa.colsum = dvec;
    pa.temp = temp;
    k_prep<<<1840 + 250 + 32 + 64, dim3(32, 8), 0, stream>>>(pa);

    // --- GCN: Y = embbf @ gcn_w; edge scatter; base term folded into fuse ---
    k_bgemm2<0><<<dim3(1, 16), 256, 0, stream>>>(embbf, wbf_gcn, nullptr, nullptr, Y,
                                                 DIMN, DIMN, 0);
    k_edgeX<<<NEDGE / 2, 256, 0, stream>>>(history, dvec, Y, Eg);
    k_fuse2<<<NSEQ * S_N, DM, 0, stream>>>(history, cur, emb, dvec, Y, gcn_b, Eg,
                                           nullE, temp, Xenc, Xbf, maskb);

    // --- encoder, L=2 ---
    for (int l = 0; l < 2; ++l) {
        const bf16* wqkv = wbf_aw + l * 262144;
        const float* bl = ab + l * 1024;
        k_bgemm2<9><<<dim3(6, 68), 256, 0, stream>>>(Xbf, wqkv, bl, nullptr, QKVbf,
                                                     256, 768, 0);
        k_mattn<false><<<NSEQ * 4, 64, 0, stream>>>(QKVbf, QKVbf + 256, QKVbf + 512,
                                                    maskb, Abf, 768, 768);
        k_bgemm_ln<<<272, 256, 0, stream>>>(Abf, wqkv + 196608, bl + 768, Xenc,
                lns + (l * 2) * DM, lnb + (l * 2) * DM, Xbf, NSEQ * S_N, 256);
        k_bgemm2<11><<<dim3(8, 68), 256, 0, stream>>>(Xbf, wbf_fw1 + l * 262144,
                fb1 + l * DFF, nullptr, Hbf, 256, DFF, 0);
        k_bgemm_ln<<<272, 256, 0, stream>>>(Hbf, wbf_fw2 + l * 262144, fb2 + l * DM, Xenc,
                lns + (l * 2 + 1) * DM, lnb + (l * 2 + 1) * DM, Xbf, NSEQ * S_N, 1024);
    }

    float* mh = Xenc;                            // 128 seqs f32
    bf16*  mc_bf = Xbf + (size_t)128 * S_N * DM; // 8 seqs bf16
    float* mc_f  = Xenc + (size_t)128 * S_N * DM;

    // --- windowed cross attention ---
    k_wcaqkv<<<144, 256, 0, stream>>>(Xbf, mc_bf, wbf_wca, wca_b, Qwbf, KVbf);
    k_mattn<true><<<128 * 4, 64, 0, stream>>>(Qwbf, KVbf, KVbf + 256, nullptr, Abf, 256, 512);
    k_bgemm2<5><<<dim3(2, 64), 256, 0, stream>>>(Abf, wbf_wca + 196608, wca_b + 768, mh, SE,
                                                 256, 256, 0);

    // --- aggregate + ial + output ---
    k_aggial<<<B_N * S_N, 256, 0, stream>>>(SE, mc_f, wbf_ial, ial_b, finalb);
    k_bgemm2<16><<<dim3(16, 4), 256, 0, stream>>>(finalb, embbf, nullptr, nullptr, out,
                                                  DIMN, C_N, C_N);
}